// Round 1
// baseline (744.001 us; speedup 1.0000x reference)
//
#include <hip/hip_runtime.h>
#include <stdint.h>

#define DEVI __device__ __forceinline__

typedef __bf16 bf16x8 __attribute__((ext_vector_type(8)));
typedef float f32x4 __attribute__((ext_vector_type(4)));
typedef unsigned short u16;

// Problem constants: B=2, S=1024, HID=2048, NH=16, HD=128, NN=16, RHID=1024, CTX=2
static constexpr float SCALE_ = 0.08838834764831845f;  // 128^-0.5

DEVI u16 f2bf(float f) {  // RNE f32->bf16 (finite inputs)
  uint32_t u = __float_as_uint(f);
  u += 0x7fffu + ((u >> 16) & 1u);
  return (u16)(u >> 16);
}
DEVI float bfraw2f(uint32_t hi) { return __uint_as_float(hi); }

// ---------------- elementwise cast fp32 -> bf16, 4/thread ----------------
__global__ void k_cast(const float* __restrict__ in, u16* __restrict__ out) {
  int i = blockIdx.x * blockDim.x + threadIdx.x;
  float4 v = ((const float4*)in)[i];
  ushort4 o;
  o.x = f2bf(v.x); o.y = f2bf(v.y); o.z = f2bf(v.z); o.w = f2bf(v.w);
  ((ushort4*)out)[i] = o;
}

// ------------- transpose+cast: in[R][C] f32 -> out[C][R] bf16 -------------
__global__ void k_transpose_cast(const float* __restrict__ in, u16* __restrict__ out,
                                 int R, int C) {
  __shared__ float t[32][33];
  int tx = threadIdx.x & 31, ty = threadIdx.x >> 5;  // 256 threads
  int c0 = blockIdx.x << 5, r0 = blockIdx.y << 5;
  #pragma unroll
  for (int rr = 0; rr < 32; rr += 8) t[ty + rr][tx] = in[(r0 + ty + rr) * C + c0 + tx];
  __syncthreads();
  #pragma unroll
  for (int rr = 0; rr < 32; rr += 8) out[(c0 + ty + rr) * R + r0 + tx] = f2bf(t[tx][ty + rr]);
}

// ---------------- m97-style bf16 GEMM: C[M][N] = A[M][K] * Bt[N][K]^T ----------------
DEVI void gl_lds16(const u16* g, u16* l) {
  // async global->LDS, 16B/lane; LDS dest must be the wave-uniform base
  __builtin_amdgcn_global_load_lds((const __attribute__((address_space(1))) void*)g,
                                   (__attribute__((address_space(3))) void*)l, 16, 0, 0);
}

template<bool OUTF32, bool RESID>
__global__ __launch_bounds__(256, 2) void k_gemm(
    const u16* __restrict__ A, const u16* __restrict__ Bt, void* __restrict__ Cv,
    const float* __restrict__ resid, int M, int N, int K, float scale) {
  __shared__ __align__(16) u16 As[128 * 32];
  __shared__ __align__(16) u16 Bs[128 * 32];
  const int nbn = N >> 7;
  const int bm = blockIdx.x / nbn, bn = blockIdx.x - bm * nbn;
  const int tid = threadIdx.x, w = tid >> 6, lane = tid & 63;
  const int wr = w >> 1, wc = w & 1;          // 2x2 wave grid, 64x64 out each
  const int lr = lane & 15, kg = lane >> 4;   // fragment row/col, k-group

  const u16* Ab = A + (size_t)bm * 128 * K;
  const u16* Bb = Bt + (size_t)bn * 128 * K;

  f32x4 acc[4][4] = {};

  for (int k0 = 0; k0 < K; k0 += 32) {
    // stage 8KB A + 8KB B: each wave issues 2+2 dwordx4 lds-loads (1KB each)
    #pragma unroll
    for (int t = 0; t < 2; t++) {
      const int ub = w * 128 + t * 64;        // wave-uniform 16B-unit base
      const int u = ub + lane;                // this lane's 16B unit
      const size_t go = (size_t)(u >> 2) * K + k0 + (u & 3) * 8;
      gl_lds16(Ab + go, &As[ub * 8]);
      gl_lds16(Bb + go, &Bs[ub * 8]);
    }
    __syncthreads();  // drains vmcnt -> tiles resident
    bf16x8 af[4], bv[4];
    #pragma unroll
    for (int m = 0; m < 4; m++) af[m] = *(const bf16x8*)&As[(wr * 64 + m * 16 + lr) * 32 + kg * 8];
    #pragma unroll
    for (int n = 0; n < 4; n++) bv[n] = *(const bf16x8*)&Bs[(wc * 64 + n * 16 + lr) * 32 + kg * 8];
    #pragma unroll
    for (int m = 0; m < 4; m++)
      #pragma unroll
      for (int n = 0; n < 4; n++)
        acc[m][n] = __builtin_amdgcn_mfma_f32_16x16x32_bf16(af[m], bv[n], acc[m][n], 0, 0, 0);
    __syncthreads();  // protect LDS from next stage
  }

  // C/D layout (m89-verified): col = lane&15, row = (lane>>4)*4 + j
  const int r0 = bm * 128 + wr * 64 + kg * 4;
  const int c0 = bn * 128 + wc * 64 + lr;
  if constexpr (OUTF32) {
    float* Co = (float*)Cv;
    #pragma unroll
    for (int m = 0; m < 4; m++)
      #pragma unroll
      for (int n = 0; n < 4; n++)
        #pragma unroll
        for (int j = 0; j < 4; j++) {
          size_t idx = (size_t)(r0 + m * 16 + j) * N + (c0 + n * 16);
          float v = acc[m][n][j] * scale;
          if constexpr (RESID) v += resid[idx];
          Co[idx] = v;
        }
  } else {
    u16* Co = (u16*)Cv;
    #pragma unroll
    for (int m = 0; m < 4; m++)
      #pragma unroll
      for (int n = 0; n < 4; n++)
        #pragma unroll
        for (int j = 0; j < 4; j++) {
          size_t idx = (size_t)(r0 + m * 16 + j) * N + (c0 + n * 16);
          Co[idx] = f2bf(acc[m][n][j] * scale);
        }
  }
}

// ---------------- local attention: 32 neighbors (16 @ s-1, 16 @ s) ----------------
// Per-batch pointers. Block = 128 threads = 2 waves, 2 heads; grid = S * NH/2.
__global__ __launch_bounds__(128, 2) void k_attn(
    const u16* __restrict__ Q, const u16* __restrict__ Kb,
    const u16* __restrict__ Vb, u16* __restrict__ O) {
  __shared__ __align__(16) u16 Kl[2][32][136];  // +8 pad: 32-way -> 4-way bank conflict
  __shared__ __align__(16) u16 Vl[2][32][136];
  __shared__ __align__(16) u16 ql[2 * 128];
  const int tid = threadIdx.x;
  const int hg = blockIdx.x & 7;      // head-pair
  const int s = blockIdx.x >> 3;      // position in [0,1024)
  const int sm1 = s ? s - 1 : 0;      // clip

  // reg-staged (padded LDS forbids global_load_lds): 2 heads x 32 x 128 bf16 K and V
  #pragma unroll
  for (int it = 0; it < 8; it++) {
    int e = (it * 128 + tid) * 8;     // [0, 8192)
    int hh = e >> 12;
    int rem = e & 4095;
    int ifull = rem >> 7, d = rem & 127;
    int ctx = ifull >> 4, i = ifull & 15;   // ctx 0 -> pos s-1, ctx 1 -> pos s
    int h = hg * 2 + hh;
    size_t g = ((size_t)(ctx ? s : sm1) * 16 + h) * 2048 + i * 128 + d;
    *(bf16x8*)&Kl[hh][ifull][d] = *(const bf16x8*)&Kb[g];
    *(bf16x8*)&Vl[hh][ifull][d] = *(const bf16x8*)&Vb[g];
  }
  if (tid < 32) *(bf16x8*)&ql[tid * 8] = *(const bf16x8*)&Q[(size_t)s * 2048 + hg * 256 + tid * 8];
  __syncthreads();

  const int w = tid >> 6, lane = tid & 63;   // wave w handles head hg*2+w
  const int ni = lane & 31, dh = lane >> 5;  // neighbor, dim-half
  float sc = 0.f;
  #pragma unroll
  for (int t = 0; t < 8; t++) {
    bf16x8 kv = *(const bf16x8*)&Kl[w][ni][dh * 64 + t * 8];
    bf16x8 qv = *(const bf16x8*)&ql[w * 128 + dh * 64 + t * 8];
    #pragma unroll
    for (int j = 0; j < 8; j++) sc += (float)kv[j] * (float)qv[j];
  }
  sc += __shfl_xor(sc, 32);                  // combine dim halves -> full dot (Q has SCALE)
  float mx = sc;
  #pragma unroll
  for (int m_ = 16; m_; m_ >>= 1) mx = fmaxf(mx, __shfl_xor(mx, m_));
  float ex = __expf(sc - mx);
  float sm = ex;
  #pragma unroll
  for (int m_ = 16; m_; m_ >>= 1) sm += __shfl_xor(sm, m_);
  float pr = ex / sm;

  float o0 = 0.f, o1 = 0.f;                  // lane owns dims 2*lane, 2*lane+1
  #pragma unroll
  for (int i2 = 0; i2 < 32; i2++) {
    float pi = __shfl(pr, i2);               // lane i2 holds p for neighbor i2
    uint32_t vv = *(const uint32_t*)&Vl[w][i2][lane * 2];
    o0 += pi * bfraw2f(vv << 16);
    o1 += pi * bfraw2f(vv & 0xffff0000u);
  }
  int h = hg * 2 + w;
  uint32_t ov = (uint32_t)f2bf(o0) | ((uint32_t)f2bf(o1) << 16);
  *(uint32_t*)&O[((size_t)s * 16 + h) * 128 + lane * 2] = ov;
}

extern "C" void kernel_launch(void* const* d_in, const int* in_sizes, int n_in,
                              void* d_out, int out_size, void* d_ws, size_t ws_size,
                              hipStream_t stream) {
  (void)in_sizes; (void)n_in; (void)out_size; (void)ws_size;
  const float* hs  = (const float*)d_in[0];  // (2,1024,2048)
  const float* ext = (const float*)d_in[1];  // (2,1024,16,1024)
  const float* Wq  = (const float*)d_in[2];  // (2048,2048)
  const float* Wk  = (const float*)d_in[3];  // (1024,2048)
  const float* Wv  = (const float*)d_in[4];  // (1024,2048)
  const float* Wo  = (const float*)d_in[5];  // (2048,2048)
  float* out = (float*)d_out;

  // ws layout (bf16), total 240 MB
  char* p = (char*)d_ws;
  auto alloc = [&](size_t elems) {
    u16* r = (u16*)p;
    p += ((elems * 2 + 255) & ~(size_t)255);
    return r;
  };
  u16* hs_bf  = alloc(4ull << 20);   // [2048][2048]
  u16* ext_bf = alloc(32ull << 20);  // [32768][1024]
  u16* Wq_t   = alloc(4ull << 20);   // [2048][2048]
  u16* Wk_t   = alloc(2ull << 20);   // [2048][1024]
  u16* Wv_t   = alloc(2ull << 20);
  u16* Wo_t   = alloc(4ull << 20);   // [2048][2048]
  u16* Qb     = alloc(4ull << 20);   // [2048][2048] (has SCALE)
  u16* Ob     = alloc(4ull << 20);   // attention out [2048][2048]
  u16* Kbuf   = alloc(32ull << 20);  // per-batch [16384][2048]
  u16* Vbuf   = alloc(32ull << 20);

  // casts + weight transposes
  k_cast<<<4096, 256, 0, stream>>>(hs, hs_bf);
  k_cast<<<32768, 256, 0, stream>>>(ext, ext_bf);
  k_transpose_cast<<<dim3(64, 64), 256, 0, stream>>>(Wq, Wq_t, 2048, 2048);
  k_transpose_cast<<<dim3(64, 32), 256, 0, stream>>>(Wk, Wk_t, 1024, 2048);
  k_transpose_cast<<<dim3(64, 32), 256, 0, stream>>>(Wv, Wv_t, 1024, 2048);
  k_transpose_cast<<<dim3(64, 64), 256, 0, stream>>>(Wo, Wo_t, 2048, 2048);

  // Q = (hs @ Wq) * SCALE
  k_gemm<false, false><<<16 * 16, 256, 0, stream>>>(hs_bf, Wq_t, Qb, nullptr,
                                                    2048, 2048, 2048, SCALE_);
  // per batch: K/V projections + attention (keeps K+V (128MB) L3-resident)
  for (int b = 0; b < 2; b++) {
    const u16* extb = ext_bf + (size_t)b * 16384 * 1024;
    k_gemm<false, false><<<128 * 16, 256, 0, stream>>>(extb, Wk_t, Kbuf, nullptr,
                                                       16384, 2048, 1024, 1.0f);
    k_gemm<false, false><<<128 * 16, 256, 0, stream>>>(extb, Wv_t, Vbuf, nullptr,
                                                       16384, 2048, 1024, 1.0f);
    k_attn<<<1024 * 8, 128, 0, stream>>>(Qb + (size_t)b * 1024 * 2048, Kbuf, Vbuf,
                                         Ob + (size_t)b * 1024 * 2048);
  }
  // out = Ob @ Wo + hs  (fp32 out, fused residual)
  k_gemm<true, true><<<16 * 16, 256, 0, stream>>>(Ob, Wo_t, out, hs,
                                                  2048, 2048, 2048, 1.0f);
}

// Round 3
// 651.927 us; speedup vs baseline: 1.1412x; 1.1412x over previous
//
#include <hip/hip_runtime.h>
#include <stdint.h>

#define DEVI __device__ __forceinline__

typedef __bf16 bf16x8 __attribute__((ext_vector_type(8)));
typedef float f32x4 __attribute__((ext_vector_type(4)));
typedef unsigned short u16;

// B=2, S=1024, HID=2048, NH=16, HD=128, NN=16, RHID=1024, CTX=2
static constexpr float SCALE_ = 0.08838834764831845f;  // 128^-0.5

DEVI u16 f2bf(float f) {  // RNE f32->bf16 (finite inputs)
  uint32_t u = __float_as_uint(f);
  u += 0x7fffu + ((u >> 16) & 1u);
  return (u16)(u >> 16);
}
DEVI float bfraw2f(uint32_t hi) { return __uint_as_float(hi); }

// ---------------- elementwise cast fp32 -> bf16, 4/thread ----------------
__global__ void k_cast(const float* __restrict__ in, u16* __restrict__ out) {
  int i = blockIdx.x * blockDim.x + threadIdx.x;
  float4 v = ((const float4*)in)[i];
  ushort4 o;
  o.x = f2bf(v.x); o.y = f2bf(v.y); o.z = f2bf(v.z); o.w = f2bf(v.w);
  ((ushort4*)out)[i] = o;
}

// ------------- transpose+cast: in[R][C] f32 -> out[C][R] bf16 -------------
__global__ void k_transpose_cast(const float* __restrict__ in, u16* __restrict__ out,
                                 int R, int C) {
  __shared__ float t[32][33];
  int tx = threadIdx.x & 31, ty = threadIdx.x >> 5;  // 256 threads
  int c0 = blockIdx.x << 5, r0 = blockIdx.y << 5;
  #pragma unroll
  for (int rr = 0; rr < 32; rr += 8) t[ty + rr][tx] = in[(r0 + ty + rr) * C + c0 + tx];
  __syncthreads();
  #pragma unroll
  for (int rr = 0; rr < 32; rr += 8) out[(c0 + ty + rr) * R + r0 + tx] = f2bf(t[tx][ty + rr]);
}

DEVI void gl_lds16(const u16* g, u16* l) {
  __builtin_amdgcn_global_load_lds((const __attribute__((address_space(1))) void*)g,
                                   (__attribute__((address_space(3))) void*)l, 16, 0, 0);
}

// ---------------- m97-style 128^2 bf16 GEMM (R1-proven) for Q/O proj ----------------
template<bool OUTF32, bool RESID>
__global__ __launch_bounds__(256, 2) void k_gemm(
    const u16* __restrict__ A, const u16* __restrict__ Bt, void* __restrict__ Cv,
    const float* __restrict__ resid, int M, int N, int K, float scale) {
  __shared__ __align__(16) u16 As[128 * 32];
  __shared__ __align__(16) u16 Bs[128 * 32];
  const int nbn = N >> 7;
  const int bm = blockIdx.x / nbn, bn = blockIdx.x - bm * nbn;
  const int tid = threadIdx.x, w = tid >> 6, lane = tid & 63;
  const int wr = w >> 1, wc = w & 1;
  const int lr = lane & 15, kg = lane >> 4;

  const u16* Ab = A + (size_t)bm * 128 * K;
  const u16* Bb = Bt + (size_t)bn * 128 * K;

  f32x4 acc[4][4] = {};

  for (int k0 = 0; k0 < K; k0 += 32) {
    #pragma unroll
    for (int t = 0; t < 2; t++) {
      const int ub = w * 128 + t * 64;
      const int u = ub + lane;
      const size_t go = (size_t)(u >> 2) * K + k0 + (u & 3) * 8;
      gl_lds16(Ab + go, &As[ub * 8]);
      gl_lds16(Bb + go, &Bs[ub * 8]);
    }
    __syncthreads();
    bf16x8 af[4], bv[4];
    #pragma unroll
    for (int m = 0; m < 4; m++) af[m] = *(const bf16x8*)&As[(wr * 64 + m * 16 + lr) * 32 + kg * 8];
    #pragma unroll
    for (int n = 0; n < 4; n++) bv[n] = *(const bf16x8*)&Bs[(wc * 64 + n * 16 + lr) * 32 + kg * 8];
    #pragma unroll
    for (int m = 0; m < 4; m++)
      #pragma unroll
      for (int n = 0; n < 4; n++)
        acc[m][n] = __builtin_amdgcn_mfma_f32_16x16x32_bf16(af[m], bv[n], acc[m][n], 0, 0, 0);
    __syncthreads();
  }

  const int r0 = bm * 128 + wr * 64 + kg * 4;
  const int c0 = bn * 128 + wc * 64 + lr;
  #pragma unroll
  for (int m = 0; m < 4; m++)
    #pragma unroll
    for (int n = 0; n < 4; n++)
      #pragma unroll
      for (int j = 0; j < 4; j++) {
        size_t idx = (size_t)(r0 + m * 16 + j) * N + (c0 + n * 16);
        float v = acc[m][n][j] * scale;
        if constexpr (OUTF32) {
          if constexpr (RESID) v += resid[idx];
          ((float*)Cv)[idx] = v;
        } else {
          ((u16*)Cv)[idx] = f2bf(v);
        }
      }
}

// ---------------- 256^2 8-phase KV GEMM: C[M][4096] = A[M][1024] * Bt[4096][1024]^T ----
// T2 slot-XOR swizzle + T3/T4 counted vmcnt + T5 setprio. 8 waves (2Mx4N), BK=64.
__global__ __launch_bounds__(512, 2) void k_kv256(
    const u16* __restrict__ A, const u16* __restrict__ Bt, u16* __restrict__ C) {
  constexpr int K = 1024, NT = K / 64, LDC = 4096;
  __shared__ __align__(16) u16 lds[65536];  // 128KB: A[2dbuf][2half][128r][64k] | B same
  char* ldsc = (char*)lds;
  const int tid = threadIdx.x, w = tid >> 6, lane = tid & 63;
  const int wr = w >> 2, wc = w & 3;             // 2x4 wave grid; per-wave out 128x64
  const int lr = lane & 15, kg = lane >> 4, x3 = lr & 7;
  const int bm = blockIdx.x >> 4, bn = blockIdx.x & 15;

  // per-thread staging source offsets (slot pre-swizzled so linear LDS dest is swizzled)
  const int u0 = tid, u1 = 512 + tid;
  const int r0s = u0 >> 3, r1s = u1 >> 3;
  const int ro0 = r0s * K + ((u0 & 7) ^ (r0s & 7)) * 8;
  const int ro1 = r1s * K + ((u1 & 7) ^ (r1s & 7)) * 8;
  const u16* Ab = A + (size_t)bm * 256 * K;
  const u16* Bb = Bt + (size_t)bn * 256 * K;

  auto stage = [&](int db2, int q, int k64) {  // q: 0=A h0, 1=A h1, 2=B h0, 3=B h1
    const int h = q & 1;
    const u16* base = (q >= 2) ? Bb : Ab;
    uint32_t dst = ((q >= 2) ? 65536u : 0u) + (uint32_t)(db2 * 2 + h) * 16384u
                   + (uint32_t)w * 1024u;
    const size_t tb = (size_t)h * 128 * K + k64;
    gl_lds16(base + tb + ro0, (u16*)(ldsc + dst));
    gl_lds16(base + tb + ro1, (u16*)(ldsc + dst + 8192u));
  };

  f32x4 acc[8][4] = {};

  #pragma unroll
  for (int q = 0; q < 4; ++q) stage(0, q, 0);   // prologue: kt=0 -> dbuf 0
  __builtin_amdgcn_sched_barrier(0);

  for (int kt = 0; kt < NT; ++kt) {
    const int c = kt & 1;
    const int nk64 = (kt + 1 < NT ? kt + 1 : kt) * 64;  // clamped (tail restages, unread)
    __builtin_amdgcn_sched_barrier(0);
    __builtin_amdgcn_s_barrier();               // B1: all waves done reading dbuf c^1
    __builtin_amdgcn_sched_barrier(0);
    stage(c ^ 1, 0, nk64);                      // issue BEFORE the wait (stays in flight)
    __builtin_amdgcn_sched_barrier(0);
    asm volatile("s_waitcnt vmcnt(2)" ::: "memory");  // kt's 8 loads done; 2 new in flight
    __builtin_amdgcn_sched_barrier(0);
    __builtin_amdgcn_s_barrier();               // B2: dbuf c resident for all waves
    __builtin_amdgcn_sched_barrier(0);

    const uint32_t a_base = (uint32_t)(c * 2 + wr) * 16384u;
    const uint32_t b_base = 65536u + (uint32_t)(c * 2 + (wc >> 1)) * 16384u;
    #pragma unroll
    for (int q = 0; q < 4; ++q) {               // 4 quadrant phases per K-tile
      if (q > 0) { stage(c ^ 1, q, nk64); __builtin_amdgcn_sched_barrier(0); }
      const int mh = q >> 1, nh = q & 1;
      bf16x8 af[4][2], bfr[2][2];
      #pragma unroll
      for (int m = 0; m < 4; ++m)
        #pragma unroll
        for (int ks = 0; ks < 2; ++ks)
          af[m][ks] = *(const bf16x8*)(ldsc + a_base + (mh * 64 + m * 16 + lr) * 128
                                       + ((((ks << 2) | kg) ^ x3) << 4));
      #pragma unroll
      for (int n = 0; n < 2; ++n)
        #pragma unroll
        for (int ks = 0; ks < 2; ++ks)
          bfr[n][ks] = *(const bf16x8*)(ldsc + b_base
                                        + ((wc & 1) * 64 + (nh * 2 + n) * 16 + lr) * 128
                                        + ((((ks << 2) | kg) ^ x3) << 4));
      __builtin_amdgcn_s_setprio(1);
      #pragma unroll
      for (int m = 0; m < 4; ++m)
        #pragma unroll
        for (int n = 0; n < 2; ++n)
          #pragma unroll
          for (int ks = 0; ks < 2; ++ks)
            acc[mh * 4 + m][nh * 2 + n] = __builtin_amdgcn_mfma_f32_16x16x32_bf16(
                af[m][ks], bfr[n][ks], acc[mh * 4 + m][nh * 2 + n], 0, 0, 0);
      __builtin_amdgcn_s_setprio(0);
    }
  }

  // C/D layout: col = lane&15, row = kg*4 + j
  const int gr0 = bm * 256 + wr * 128 + kg * 4;
  const int gc0 = bn * 256 + wc * 64 + lr;
  #pragma unroll
  for (int m = 0; m < 8; ++m)
    #pragma unroll
    for (int n = 0; n < 4; ++n)
      #pragma unroll
      for (int j = 0; j < 4; ++j)
        C[(size_t)(gr0 + m * 16 + j) * LDC + gc0 + n * 16] = f2bf(acc[m][n][j]);
}

// ---------------- local attention (R0-proven), merged-KV layout ----------------
// KV: [16384][4096] per batch; K at col i*128+d, V at col 2048+i*128+d.
__global__ __launch_bounds__(128, 2) void k_attn(
    const u16* __restrict__ Q, const u16* __restrict__ KV, u16* __restrict__ O) {
  __shared__ __align__(16) u16 Kl[2][32][136];  // +8 pad: cuts bank conflicts
  __shared__ __align__(16) u16 Vl[2][32][136];
  __shared__ __align__(16) u16 ql[2 * 128];
  const int tid = threadIdx.x;
  const int hg = blockIdx.x & 7;      // head-pair
  const int s = blockIdx.x >> 3;
  const int sm1 = s ? s - 1 : 0;

  #pragma unroll
  for (int it = 0; it < 8; it++) {
    int e = (it * 128 + tid) * 8;     // [0, 8192)
    int hh = e >> 12;
    int rem = e & 4095;
    int ifull = rem >> 7, d = rem & 127;
    int ctx = ifull >> 4, i = ifull & 15;   // ctx 0 -> pos s-1, ctx 1 -> pos s
    int h = hg * 2 + hh;
    size_t g = ((size_t)(ctx ? s : sm1) * 16 + h) * 4096 + i * 128 + d;
    *(bf16x8*)&Kl[hh][ifull][d] = *(const bf16x8*)&KV[g];
    *(bf16x8*)&Vl[hh][ifull][d] = *(const bf16x8*)&KV[g + 2048];
  }
  if (tid < 32) *(bf16x8*)&ql[tid * 8] = *(const bf16x8*)&Q[(size_t)s * 2048 + hg * 256 + tid * 8];
  __syncthreads();

  const int w = tid >> 6, lane = tid & 63;   // wave w handles head hg*2+w
  const int ni = lane & 31, dh = lane >> 5;  // neighbor, dim-half
  float sc = 0.f;
  #pragma unroll
  for (int t = 0; t < 8; t++) {
    bf16x8 kv = *(const bf16x8*)&Kl[w][ni][dh * 64 + t * 8];
    bf16x8 qv = *(const bf16x8*)&ql[w * 128 + dh * 64 + t * 8];
    #pragma unroll
    for (int j = 0; j < 8; j++) sc += (float)kv[j] * (float)qv[j];
  }
  sc += __shfl_xor(sc, 32);                  // combine dim halves (Q carries SCALE)
  float mx = sc;
  #pragma unroll
  for (int m_ = 16; m_; m_ >>= 1) mx = fmaxf(mx, __shfl_xor(mx, m_));
  float ex = __expf(sc - mx);
  float sm = ex;
  #pragma unroll
  for (int m_ = 16; m_; m_ >>= 1) sm += __shfl_xor(sm, m_);
  float pr = ex / sm;

  float o0 = 0.f, o1 = 0.f;                  // lane owns dims 2*lane, 2*lane+1
  #pragma unroll
  for (int i2 = 0; i2 < 32; i2++) {
    float pi = __shfl(pr, i2);
    uint32_t vv = *(const uint32_t*)&Vl[w][i2][lane * 2];
    o0 += pi * bfraw2f(vv << 16);
    o1 += pi * bfraw2f(vv & 0xffff0000u);
  }
  int h = hg * 2 + w;
  uint32_t ov = (uint32_t)f2bf(o0) | ((uint32_t)f2bf(o1) << 16);
  *(uint32_t*)&O[((size_t)s * 16 + h) * 128 + lane * 2] = ov;
}

extern "C" void kernel_launch(void* const* d_in, const int* in_sizes, int n_in,
                              void* d_out, int out_size, void* d_ws, size_t ws_size,
                              hipStream_t stream) {
  (void)in_sizes; (void)n_in; (void)out_size; (void)ws_size;
  const float* hs  = (const float*)d_in[0];  // (2,1024,2048)
  const float* ext = (const float*)d_in[1];  // (2,1024,16,1024)
  const float* Wq  = (const float*)d_in[2];  // (2048,2048)
  const float* Wk  = (const float*)d_in[3];  // (1024,2048)
  const float* Wv  = (const float*)d_in[4];  // (1024,2048)
  const float* Wo  = (const float*)d_in[5];  // (2048,2048)
  float* out = (float*)d_out;

  // ws layout (bf16), total 240 MB (R0-proven budget)
  char* p = (char*)d_ws;
  auto alloc = [&](size_t elems) {
    u16* r = (u16*)p;
    p += ((elems * 2 + 255) & ~(size_t)255);
    return r;
  };
  u16* hs_bf  = alloc(4ull << 20);   // [2048][2048]; reused as Ob after Q-GEMM
  u16* ext_bf = alloc(32ull << 20);  // [32768][1024]
  u16* Wq_t   = alloc(4ull << 20);   // [2048][2048]
  u16* Wkv_t  = alloc(8ull << 20);   // [4096][1024]: rows 0..2047 Wk^T, 2048..4095 Wv^T
  u16* Wo_t   = alloc(4ull << 20);   // [2048][2048]
  u16* Qb     = alloc(4ull << 20);   // [2048][2048] (has SCALE)
  u16* KVbuf  = alloc(64ull << 20);  // per-batch [16384][4096]
  u16* Ob     = hs_bf;               // attention out, reuses hs_bf region

  k_cast<<<4096, 256, 0, stream>>>(hs, hs_bf);
  k_cast<<<32768, 256, 0, stream>>>(ext, ext_bf);
  k_transpose_cast<<<dim3(64, 64), 256, 0, stream>>>(Wq, Wq_t, 2048, 2048);
  k_transpose_cast<<<dim3(64, 32), 256, 0, stream>>>(Wk, Wkv_t, 1024, 2048);
  k_transpose_cast<<<dim3(64, 32), 256, 0, stream>>>(Wv, Wkv_t + (2048ull * 1024), 1024, 2048);
  k_transpose_cast<<<dim3(64, 64), 256, 0, stream>>>(Wo, Wo_t, 2048, 2048);

  // Q = (hs @ Wq) * SCALE  (consumes hs_bf before Ob reuse)
  k_gemm<false, false><<<256, 256, 0, stream>>>(hs_bf, Wq_t, Qb, nullptr,
                                                2048, 2048, 2048, SCALE_);
  for (int b = 0; b < 2; b++) {
    const u16* extb = ext_bf + (size_t)b * 16384 * 1024;
    k_kv256<<<64 * 16, 512, 0, stream>>>(extb, Wkv_t, KVbuf);
    k_attn<<<1024 * 8, 128, 0, stream>>>(Qb + (size_t)b * 1024 * 2048, KVbuf,
                                         Ob + (size_t)b * 1024 * 2048);
  }
  // out = Ob @ Wo + hs (f32, fused residual)
  k_gemm<true, true><<<256, 256, 0, stream>>>(Ob, Wo_t, out, hs,
                                              2048, 2048, 2048, 1.0f);
}